// Round 6
// baseline (177.786 us; speedup 1.0000x reference)
//
#include <hip/hip_runtime.h>

// out[p][f] = sum_s x[p][s] * K[s][f];  P = 393,216, K 64x64 fp32.
//
// R10: five nulls (R5/R6/R7/R8b/R9 all 59.4-60.8us) localize the limiter:
// vmcnt is ONE in-order counter for loads AND stores. Every variant's
// load-wait (compiler-emitted: before staging ds_write / register use /
// barrier) transitively forces ALL OLDER STORES retired. Store-ack under a
// 98MB streaming write is HBM-queue slow -> each wave's loop period is
// gated on store retirement (R9: 12k cy/tile vs 700 cy compute), write BW
// starves at 1.6 TB/s. The write-only fill (no waits ever) does 6.7 TB/s.
// Fix: own the waits. global_load_lds staging (compiler can't track it ->
// no auto-waits) + hand asm s_waitcnt vmcnt(16) steady-state = tolerate 2
// iterations of outstanding stores + 2 in-flight tiles; stores are never
// drained in the loop. No barriers in loop. Linear-LDS bank conflicts
// fixed by pre-swizzling the per-lane GLOBAL source (m173): chunk c of a
// tile lands at LDS slot c ^ (row&7) -> A-frag b128 reads are 2-way (free);
// global coverage per 64B granule unchanged (XOR within 128B).
// LDS: 4 waves x 3 slots x 4KB ring (48KB) + out-transpose scratch 17.4KB
// (overlaid with K-staging, barriers only in prologue) = 65KB -> 2 blk/CU.
// Numerics unchanged (3-term bf16 hi/lo, absmax 0.03125).
// Prediction: dur 60 -> 30-42us, hbm 2.5 -> >=3.8 TB/s, WRITE ~98MB.
// If null: 6 structures incl. hand-scheduled pipeline all ~60us -> ROOFLINE.

#define THREADS 256
#define WPB     4
#define NT      12          // tiles/wave; 512 blk * 4 * 12 = 24576 exact
#define NSLOT   3
#define OROW    68

typedef __attribute__((ext_vector_type(8))) short bf16x8;
typedef __attribute__((ext_vector_type(4))) float f32x4;

static __device__ __forceinline__ unsigned short bf16_rne(float f) {
    unsigned int u = __float_as_uint(f);
    u += 0x7fffu + ((u >> 16) & 1u);
    return (unsigned short)(u >> 16);
}
static __device__ __forceinline__ float bf16f(unsigned short h) {
    return __uint_as_float((unsigned int)h << 16);
}

__global__ __launch_bounds__(THREADS)
void dct_kernel(const float* __restrict__ x,
                const float* __restrict__ Kmat,
                float* __restrict__ out) {
    __shared__ __align__(16) float xslot[WPB][NSLOT][1024];  // 48 KB ring
    __shared__ __align__(16) float oscr[WPB][16][OROW];      // 17.4 KB

    // K-staging overlays oscr (prologue only; fenced by __syncthreads)
    short* bhi = (short*)&oscr[0][0][0];
    short* blo = bhi + 8 * 64 * 8;

    const int tid  = threadIdx.x;
    const int lane = tid & 63;
    const int wv   = tid >> 6;
    const int l15  = lane & 15;
    const int quad = lane >> 4;

    const int totw = (int)gridDim.x * WPB;              // 2048 waves
    const long long wt0 = (long long)blockIdx.x * WPB + wv;
    const char* tbase = (const char*)x + wt0 * 4096;
    const long long TSB = (long long)totw * 4096;       // byte step per s
    float* dst = out + wt0 * 1024;
    const long long SSTEP = (long long)totw * 1024;     // float step per s

    // per-lane swizzled global byte offsets for the 4 gload_lds per tile:
    // LDS chunk-slot s=i*64+lane receives global chunk c = s ^ ((s>>4)&7)
    int goff[4];
#pragma unroll
    for (int i = 0; i < 4; ++i) {
        int sc = i * 64 + lane;
        goff[i] = (sc ^ ((sc >> 4) & 7)) * 16;
    }

    // ---- issue tiles 0,1 into slots 0,1 (latency hides under K build) ----
#pragma unroll
    for (int t = 0; t < 2; ++t)
#pragma unroll
        for (int i = 0; i < 4; ++i)
            __builtin_amdgcn_global_load_lds(
                (const __attribute__((address_space(1))) unsigned int*)(tbase + (long long)t * TSB + goff[i]),
                (__attribute__((address_space(3))) unsigned int*)&xslot[wv][t][i * 256],
                16, 0, 0);

    // ---- build K bf16 hi/lo B-frags (overlay); wave wv: combos 2wv,2wv+1 --
#pragma unroll
    for (int cc = 0; cc < 2; ++cc) {
        const int combo = wv * 2 + cc;
        const int kc = combo >> 2, ft = combo & 3;
        short hh[8], ll[8];
#pragma unroll
        for (int j = 0; j < 8; ++j) {
            float v = Kmat[(kc * 32 + quad * 8 + j) * 64 + ft * 16 + l15];
            unsigned short h = bf16_rne(v);
            hh[j] = (short)h;
            ll[j] = (short)bf16_rne(v - bf16f(h));
        }
        *(bf16x8*)&bhi[(combo * 64 + lane) * 8] = *(bf16x8*)hh;
        *(bf16x8*)&blo[(combo * 64 + lane) * 8] = *(bf16x8*)ll;
    }
    __syncthreads();

    bf16x8 Bh[8], Bl[8];
#pragma unroll
    for (int c = 0; c < 8; ++c) {
        Bh[c] = *(const bf16x8*)&bhi[(c * 64 + lane) * 8];
        Bl[c] = *(const bf16x8*)&blo[(c * 64 + lane) * 8];
    }
    __syncthreads();   // all waves done reading overlay before oscr reuse

    // ---- main loop: no barriers; hand-counted vmcnt; stores never drained -
#pragma unroll
    for (int s = 0; s < NT; ++s) {
        const int cur = s % NSLOT;

        if (s + 2 < NT) {
            const int nx = (s + 2) % NSLOT;
            const char* tb = tbase + (long long)(s + 2) * TSB;
#pragma unroll
            for (int i = 0; i < 4; ++i)
                __builtin_amdgcn_global_load_lds(
                    (const __attribute__((address_space(1))) unsigned int*)(tb + goff[i]),
                    (__attribute__((address_space(3))) unsigned int*)&xslot[wv][nx][i * 256],
                    16, 0, 0);
        }

        // guarantee tile s staged; tolerate everything newer (incl. the
        // previous 2 iterations' stores) outstanding. N = #vm ops issued
        // after tile-s's 4 gloads: steady {st,g,st,g} = 16; ramp/tail less.
        if (s == 0)           asm volatile("s_waitcnt vmcnt(8)"  ::: "memory");
        else if (s == 1)      asm volatile("s_waitcnt vmcnt(12)" ::: "memory");
        else if (s + 2 < NT)  asm volatile("s_waitcnt vmcnt(16)" ::: "memory");
        else if (s + 1 < NT)  asm volatile("s_waitcnt vmcnt(12)" ::: "memory");
        else                  asm volatile("s_waitcnt vmcnt(8)"  ::: "memory");
        __builtin_amdgcn_sched_barrier(0);

        // ---- A-frags from swizzled slot: 2-way banks (free) ----
        const float* slotF = &xslot[wv][cur][0];
        bf16x8 Ahi[2], Alo[2];
#pragma unroll
        for (int kc = 0; kc < 2; ++kc) {
            const int c1 = l15 * 16 + kc * 8 + quad * 2;   // global chunk
            const int m  = l15 & 7;
            float av[8];
            *(f32x4*)&av[0] = *(const f32x4*)(slotF + ((c1 ^ m) << 2));
            *(f32x4*)&av[4] = *(const f32x4*)(slotF + (((c1 + 1) ^ m) << 2));
            short ah[8], al[8];
#pragma unroll
            for (int j = 0; j < 8; ++j) {
                unsigned short h = bf16_rne(av[j]);
                ah[j] = (short)h;
                al[j] = (short)bf16_rne(av[j] - bf16f(h));
            }
            Ahi[kc] = *(bf16x8*)ah;
            Alo[kc] = *(bf16x8*)al;
        }

        f32x4 acc[4];
#pragma unroll
        for (int t = 0; t < 4; ++t) acc[t] = (f32x4){0.f, 0.f, 0.f, 0.f};
#pragma unroll
        for (int kc = 0; kc < 2; ++kc)
#pragma unroll
            for (int ft = 0; ft < 4; ++ft) {
                const int c = kc * 4 + ft;
                acc[ft] = __builtin_amdgcn_mfma_f32_16x16x32_bf16(Ahi[kc], Bh[c], acc[ft], 0, 0, 0);
                acc[ft] = __builtin_amdgcn_mfma_f32_16x16x32_bf16(Alo[kc], Bh[c], acc[ft], 0, 0, 0);
                acc[ft] = __builtin_amdgcn_mfma_f32_16x16x32_bf16(Ahi[kc], Bl[c], acc[ft], 0, 0, 0);
            }

        // ---- epilogue: wave-private transpose -> contiguous nt dwordx4 ----
#pragma unroll
        for (int ft = 0; ft < 4; ++ft)
#pragma unroll
            for (int r = 0; r < 4; ++r)
                oscr[wv][quad * 4 + r][ft * 16 + l15] = acc[ft][r];
        float* ob = dst + (long long)s * SSTEP;
#pragma unroll
        for (int i = 0; i < 4; ++i) {
            f32x4 v = *(const f32x4*)&oscr[wv][i * 4 + quad][l15 * 4];
            __builtin_nontemporal_store(v, (f32x4*)(ob + i * 256 + lane * 4));
        }
    }
}

extern "C" void kernel_launch(void* const* d_in, const int* in_sizes, int n_in,
                              void* d_out, int out_size, void* d_ws, size_t ws_size,
                              hipStream_t stream) {
    const float* x = (const float*)d_in[0];   // (8,3,1024,1024) fp32
    const float* K = (const float*)d_in[1];   // (64,64) fp32
    float* out = (float*)d_out;

    const int total = in_sizes[0];            // 25,165,824 floats
    const int num_patches = total / 64;       // 393,216
    const int wave_tiles  = num_patches / 16; // 24,576
    const int blocks = wave_tiles / (WPB * NT);  // 512, exact

    dct_kernel<<<blocks, THREADS, 0, stream>>>(x, K, out);
}